// Round 12
// baseline (164.054 us; speedup 1.0000x reference)
//
#include <hip/hip_runtime.h>

// Sizes (fixed for this problem)
constexpr int B  = 2,  CIN = 2,  H = 64, W = 64, T = 350;
constexpr int C1 = 8;                       // conv1 out channels
constexpr int TO = 700, HO = 128, WO = 64;
constexpr int HW = H * W;                   // 4096

#define DEC 0.05000000074505806f            // (float)(1.0 - 0.95)

// ---------------------------------------------------------------------------
// Kernel 0: transpose x [B,2,H,W,T] -> xT [B,2,T,H,W] so conv reads coalesce.
// ---------------------------------------------------------------------------
__global__ void __launch_bounds__(256) transpose_kernel(
    const float* __restrict__ x, float* __restrict__ xT) {
  __shared__ float tile[64][65];
  int bid   = blockIdx.x;
  int tTile = bid % 6;            // 6 tiles of 64 cover T=350
  int slice = bid / 6;            // (b*2+ci)*64 + h
  int h  = slice % H;
  int bc = slice / H;             // b*2+ci
  int t0 = tTile * 64;
  int tx = threadIdx.x & 63;
  int tz = threadIdx.x >> 6;      // 0..3

  const float* src = x + ((long)bc * H + h) * (long)(W * T);
#pragma unroll
  for (int i = 0; i < 16; ++i) {
    int w = tz * 16 + i;
    int t = t0 + tx;
    tile[w][tx] = (t < T) ? src[(long)w * T + t] : 0.0f;
  }
  __syncthreads();
  float* dst = xT + ((long)bc * T) * HW + h * 64;
#pragma unroll
  for (int i = 0; i < 16; ++i) {
    int tl = tz * 16 + i;
    int t  = t0 + tl;
    if (t < T) dst[(long)t * HW + tx] = tile[tx][tl];
  }
}

// ---------------------------------------------------------------------------
// Kernel A (barrier-free): conv1(5x5 over T,H) + bias + relu + LIF1 + delta
// -> d8 int8 [b][t][hw][ci].
// Thread = one (h,w) column for fixed (b,co,chunk). Block = 256 = 4h x 64w
// (wave = 1 h x 64 w -> each of the 10 taps/step is one coalesced 256B row
// read; L1 catches the 5x dh reuse across the block's waves). NO LDS, NO
// barriers, NO vmcnt: latency hidden by 16 waves/CU of TLP + 1-step
// register prefetch (fr bank holds tau=t+2; refilled with t+3 after use).
// 4-slot register window, slot = tau & 3 (ts % 4 == 0 -> static indices).
// Weights per-thread VGPRs, zeroed for out-of-range h+dh-2 (clamped loads
// then contribute nothing). 4 T-chunks of 88 with 16-step warm-up
// (0.05^16 ~ 1e-21 -> bitwise-converged; semantics proven r8-r10).
// ---------------------------------------------------------------------------
__global__ void __launch_bounds__(256) colconv_kernel(
    const float* __restrict__ xT, const float* __restrict__ w1,
    const float* __restrict__ b1, signed char* __restrict__ d8) {
  const int tid = threadIdx.x;
  const int bid = blockIdx.x;
  const int hblk  = bid & 15;
  const int chunk = (bid >> 4) & 3;
  const int co    = (bid >> 6) & 7;         // block-uniform
  const int b     = bid >> 9;
  const int w  = tid & 63;
  const int h  = hblk * 4 + (tid >> 6);

  const int tstore = chunk * 88;
  const int ts     = chunk ? tstore - 16 : 0;       // multiple of 4
  const int te     = (tstore + 88 < T) ? tstore + 88 : T;
  const int te_pad = ts + ((te - ts + 3) & ~3);     // pad to unroll-4

  // Weights (VGPR; zero taps whose h+dh-2 is out of range) + element offsets.
  float wt[2][5][5];
  int   voffe[2][5];
#pragma unroll
  for (int ci = 0; ci < 2; ++ci)
#pragma unroll
    for (int dh = 0; dh < 5; ++dh) {
      int hh = h + dh - 2;
      bool hv = (hh >= 0) && (hh < H);
      int hc = hh < 0 ? 0 : (hh > H - 1 ? H - 1 : hh);
#pragma unroll
      for (int dt = 0; dt < 5; ++dt)
        wt[ci][dt][dh] = hv ? w1[((co * 2 + ci) * 5 + dt) * 5 + dh] : 0.0f;
      voffe[ci][dh] = (b * 2 + ci) * T * HW + hc * 64 + w;
    }
  float bias = b1[co];

  // Window init: slot = tau & 3 for taus ts-2..ts+1; fr = tau ts+2.
  float win[2][5][4];
  float fr[2][5];
#pragma unroll
  for (int ci = 0; ci < 2; ++ci)
#pragma unroll
    for (int dh = 0; dh < 5; ++dh) {
      const float* bp = xT + voffe[ci][dh];
      win[ci][dh][2] = (ts >= 2) ? bp[(long)(ts - 2) * HW] : 0.0f;
      win[ci][dh][3] = (ts >= 1) ? bp[(long)(ts - 1) * HW] : 0.0f;
      win[ci][dh][0] = bp[(long)(ts + 0) * HW];
      win[ci][dh][1] = bp[(long)(ts + 1) * HW];
      fr[ci][dh]     = bp[(long)(ts + 2) * HW];
    }

  signed char* dsto = d8 + ((long)(b * T)) * (HW * C1) + (h * 64 + w) * 8 + co;
  const float* xTt = xT + (long)(ts + 3) * HW;      // base for tau = t+3 loads

  float y = 0.0f, sprev = 0.0f;
  for (int tb = ts; tb < te_pad; tb += 4) {
#pragma unroll
    for (int u = 0; u < 4; ++u) {
      int t = tb + u;                               // t & 3 == u
      float ac0 = bias, ac1 = 0.f, ac2 = 0.f, ac3 = 0.f;
#pragma unroll
      for (int ci = 0; ci < 2; ++ci)
#pragma unroll
        for (int dt = 0; dt < 5; ++dt)
#pragma unroll
          for (int dh = 0; dh < 5; ++dh) {
            const int q = (ci * 25 + dt * 5 + dh) & 3;
            // tau = t-2+dt: dt<4 -> slot (u+2+dt)&3; dt==4 -> fr (tau t+2)
            float tap = (dt < 4) ? win[ci][dh][(u + 2 + dt) & 3] : fr[ci][dh];
            float p = tap * wt[ci][dt][dh];
            if (q == 0) ac0 += p;
            else if (q == 1) ac1 += p;
            else if (q == 2) ac2 += p;
            else ac3 += p;
          }
      float a = fmaxf((ac0 + ac1) + (ac2 + ac3), 0.0f);
      y = fmaf(DEC, y, a);
      float s = (y >= 1.0f) ? 1.0f : 0.0f;
      if (t >= tstore && t < te) {
        float dlt = (t == 0) ? 0.0f : (s - sprev);
        dsto[(long)t * (HW * C1)] = (signed char)dlt;
      }
      sprev = s;
      y = (s != 0.0f) ? 0.0f : y;
      // advance window with fr (tau t+2 -> slot (u+2)&3), refill fr = tau t+3
#pragma unroll
      for (int ci = 0; ci < 2; ++ci)
#pragma unroll
        for (int dh = 0; dh < 5; ++dh)
          win[ci][dh][(u + 2) & 3] = fr[ci][dh];
      if (t + 3 < T) {                              // wave-uniform branch
#pragma unroll
        for (int ci = 0; ci < 2; ++ci)
#pragma unroll
          for (int dh = 0; dh < 5; ++dh)
            fr[ci][dh] = xTt[voffe[ci][dh]];
      } else {
#pragma unroll
        for (int ci = 0; ci < 2; ++ci)
#pragma unroll
          for (int dh = 0; dh < 5; ++dh)
            fr[ci][dh] = 0.0f;                      // conv zero-pad beyond T
      }
      xTt += HW;
    }
  }
}

// ---------------------------------------------------------------------------
// Kernel B: deconv(2x2,s2) + bias + relu + conv2(1x1) + LIF2 -> out
// d8 [b][t][hw][ci]: one 8B uint2 load per pair-step, prefetched 1 iter ahead.
// out layout [B,2,H',W',T']; LDS-staged transposed flush. 25 chunks of 28.
// (unchanged -- passed rounds 10-11)
// ---------------------------------------------------------------------------
__global__ void __launch_bounds__(64) stage2_kernel(
    const signed char* __restrict__ d8, const float* __restrict__ dw,
    const float* __restrict__ db, const float* __restrict__ cw,
    const float* __restrict__ cb, float* __restrict__ out) {
  __shared__ float SB[2][64][17];
  int bid   = blockIdx.x;
  int chunk = bid % 25;
  int rest  = bid / 25;
  int hp = rest & 127;
  int b  = rest >> 7;
  int wp = threadIdx.x;

  int h  = hp >> 1;
  int kh = 1 - (hp & 1);

  float dwk0[2][8], dwk1[2][8];
#pragma unroll
  for (int c = 0; c < 2; ++c)
#pragma unroll
    for (int ci = 0; ci < 8; ++ci) {
      dwk0[c][ci] = dw[((c * 8 + ci) * 2 + 0) * 2 + kh];
      dwk1[c][ci] = dw[((c * 8 + ci) * 2 + 1) * 2 + kh];
    }
  float db0 = db[0], db1 = db[1];
  float cw00 = cw[0], cw01 = cw[1], cw10 = cw[2], cw11 = cw[3];
  float cb0 = cb[0], cb1 = cb[1];

  int t0 = chunk * 28;
  int t1 = t0 + 28;
  int tw = (t0 - 16 > 0) ? t0 - 16 : 0;

  const signed char* dbase = d8 + (((long)b * T) * HW + h * 64 + wp) * C1;
  const long tstride = (long)HW * C1;
  float* outb = out + ((long)b * 2 * HO) * (long)(WO * TO);

  float y0 = 0.0f, y1 = 0.0f;
  uint2 dc = *reinterpret_cast<const uint2*>(dbase + (long)(tw >> 1) * tstride);
  for (int tp = tw; tp < t1; tp += 2) {
    int tn = (tp + 2 < t1) ? ((tp + 2) >> 1) : ((t1 - 1) >> 1);
    uint2 dn = *reinterpret_cast<const uint2*>(dbase + (long)tn * tstride);

    float dv[8];
#pragma unroll
    for (int ci = 0; ci < 4; ++ci) {
      dv[ci]     = (float)(signed char)((dc.x >> (8 * ci)) & 0xff);
      dv[ci + 4] = (float)(signed char)((dc.y >> (8 * ci)) & 0xff);
    }

#pragma unroll
    for (int par = 0; par < 2; ++par) {
      int tpp = tp + par;
      float v0 = db0, v1 = db1;
      if (par == 0) {
#pragma unroll
        for (int ci = 0; ci < 8; ++ci) {
          v0 = fmaf(dv[ci], dwk1[0][ci], v0);
          v1 = fmaf(dv[ci], dwk1[1][ci], v1);
        }
      } else {
#pragma unroll
        for (int ci = 0; ci < 8; ++ci) {
          v0 = fmaf(dv[ci], dwk0[0][ci], v0);
          v1 = fmaf(dv[ci], dwk0[1][ci], v1);
        }
      }
      v0 = fmaxf(v0, 0.0f);
      v1 = fmaxf(v1, 0.0f);
      float u0 = fmaf(cw00, v0, fmaf(cw01, v1, cb0));
      float u1 = fmaf(cw10, v0, fmaf(cw11, v1, cb1));
      y0 = fmaf(DEC, y0, u0);
      y1 = fmaf(DEC, y1, u1);
      float s0 = (y0 >= 1.0f) ? 1.0f : 0.0f;
      float s1 = (y1 >= 1.0f) ? 1.0f : 0.0f;
      y0 = (s0 != 0.0f) ? 0.0f : y0;
      y1 = (s1 != 0.0f) ? 0.0f : y1;

      if (tpp >= t0) {
        int k = (tpp - t0) & 15;
        SB[0][wp][k] = s0;
        SB[1][wp][k] = s1;
        if (par == 1 && (k == 15 || tpp == t1 - 1)) {
          __syncthreads();
          int Kc  = k + 1;
          int t0f = tpp - k;
#pragma unroll
          for (int o = 0; o < 2; ++o) {
            float* ob = outb + ((long)(o * HO + hp)) * (long)(WO * TO);
#pragma unroll
            for (int i = 0; i < 4; ++i) {
              int idx = (i << 6) + wp;
              int r   = idx >> 2;
              int c   = (idx & 3) << 2;
              if (c < Kc) {
                float4 vv;
                vv.x = SB[o][r][c + 0];
                vv.y = SB[o][r][c + 1];
                vv.z = SB[o][r][c + 2];
                vv.w = SB[o][r][c + 3];
                *reinterpret_cast<float4*>(ob + (long)r * TO + (t0f + c)) = vv;
              }
            }
          }
          __syncthreads();
        }
      }
    }
    dc = dn;
  }
}

// ---------------------------------------------------------------------------
extern "C" void kernel_launch(void* const* d_in, const int* in_sizes, int n_in,
                              void* d_out, int out_size, void* d_ws, size_t ws_size,
                              hipStream_t stream) {
  const float* x  = (const float*)d_in[0];
  const float* w1 = (const float*)d_in[1];
  const float* b1 = (const float*)d_in[2];
  const float* dw = (const float*)d_in[3];
  const float* db = (const float*)d_in[4];
  const float* cw = (const float*)d_in[5];
  const float* cb = (const float*)d_in[6];
  float* out = (float*)d_out;

  float* xT = (float*)d_ws;                                   // 22.94 MB
  signed char* d8 = (signed char*)d_ws + (size_t)B * CIN * T * HW * 4;  // +22.94 MB

  // 1) transpose x -> xT
  transpose_kernel<<<dim3(B * CIN * H * 6), dim3(256), 0, stream>>>(x, xT);
  // 2) conv1+relu+LIF1+delta -> d8 (barrier-free column kernel, 4 T-chunks)
  colconv_kernel<<<dim3(B * 8 * 4 * 16), dim3(256), 0, stream>>>(xT, w1, b1, d8);
  // 3) deconv+relu+conv2(1x1)+LIF2 -> out (25 T'-chunks of 28)
  stage2_kernel<<<dim3(B * HO * 25), dim3(64), 0, stream>>>(d8, dw, db, cw, cb, out);
}

// Round 13
// 126.691 us; speedup vs baseline: 1.2949x; 1.2949x over previous
//
#include <hip/hip_runtime.h>

// Sizes (fixed for this problem)
constexpr int B  = 2,  CIN = 2,  H = 64, W = 64, T = 350;
constexpr int C1 = 8;                       // conv1 out channels
constexpr int TO = 700, HO = 128, WO = 64;
constexpr int HW = H * W;                   // 4096

#define DEC 0.05000000074505806f            // (float)(1.0 - 0.95)

// ---------------------------------------------------------------------------
// Kernel 0: transpose x [B,2,H,W,T] -> xT [B,2,T,H,W] so conv reads coalesce.
// ---------------------------------------------------------------------------
__global__ void __launch_bounds__(256) transpose_kernel(
    const float* __restrict__ x, float* __restrict__ xT) {
  __shared__ float tile[64][65];
  int bid   = blockIdx.x;
  int tTile = bid % 6;            // 6 tiles of 64 cover T=350
  int slice = bid / 6;            // (b*2+ci)*64 + h
  int h  = slice % H;
  int bc = slice / H;             // b*2+ci
  int t0 = tTile * 64;
  int tx = threadIdx.x & 63;
  int tz = threadIdx.x >> 6;      // 0..3

  const float* src = x + ((long)bc * H + h) * (long)(W * T);
#pragma unroll
  for (int i = 0; i < 16; ++i) {
    int w = tz * 16 + i;
    int t = t0 + tx;
    tile[w][tx] = (t < T) ? src[(long)w * T + t] : 0.0f;
  }
  __syncthreads();
  float* dst = xT + ((long)bc * T) * HW + h * 64;
#pragma unroll
  for (int i = 0; i < 16; ++i) {
    int tl = tz * 16 + i;
    int t  = t0 + tl;
    if (t < T) dst[(long)t * HW + tx] = tile[tx][tl];
  }
}

// ---------------------------------------------------------------------------
// async global->LDS, 16 bytes per lane (wave-uniform LDS base + lane*16)
// ---------------------------------------------------------------------------
__device__ __forceinline__ void gload_lds16(const float* g, float* l) {
  __builtin_amdgcn_global_load_lds(
      (const __attribute__((address_space(1))) unsigned int*)g,
      (__attribute__((address_space(3))) unsigned int*)l, 16, 0, 0);
}

// ---------------------------------------------------------------------------
// Kernel A: conv1(5x5 over T,H) + bias + relu + LIF1 + delta -> d8 int8
// d8 layout: [b][t][ci][hw]  (contiguous 64B/wave spike stores)
// VERBATIM round-4 kernel (measured ~40us): block 512 = (co 0..7)x(w 0..63),
// grid (b,h,2). Double-buffered 112KB LDS, superstep S=20, 7 gload_lds16
// issues/buffer, counted vmcnt(7) + raw s_barrier.
// ---------------------------------------------------------------------------
__global__ void __launch_bounds__(512) convlif_kernel(
    const float* __restrict__ xT, const float* __restrict__ w1,
    const float* __restrict__ b1, signed char* __restrict__ d8) {
  __shared__ float buf[2][224 * 64];        // 112 KiB
  const int tid = threadIdx.x;
  const int bid = blockIdx.x;
  const int chunk = bid & 1;
  const int rest  = bid >> 1;
  const int h = rest & 63;
  const int b = rest >> 6;
  const int w  = tid & 63;
  const int co = tid >> 6;                  // == wave id

  // Weights for this co; zero rows whose h+dh-2 is out of range.
  float wt[2][5][5];
#pragma unroll
  for (int ci = 0; ci < 2; ++ci)
#pragma unroll
    for (int dt = 0; dt < 5; ++dt)
#pragma unroll
      for (int dh = 0; dh < 5; ++dh)
        wt[ci][dt][dh] = w1[((co * 2 + ci) * 5 + dt) * 5 + dh];
  float bias = b1[co];

  // Clamped row bases for the one-time window init (global reads).
  const float* basep[2][5];
#pragma unroll
  for (int ci = 0; ci < 2; ++ci)
#pragma unroll
    for (int dh = 0; dh < 5; ++dh) {
      int hh = h + dh - 2;
      bool hv = (hh >= 0) && (hh < H);
      int hc = hh < 0 ? 0 : (hh > H - 1 ? H - 1 : hh);
      basep[ci][dh] = xT + ((long)((b * 2 + ci) * T)) * HW + hc * 64 + w;
      if (!hv) {
#pragma unroll
        for (int dt = 0; dt < 5; ++dt) wt[ci][dt][dh] = 0.0f;
      }
    }

  // Per-thread staging descriptors: 7 issues x 32 rows; row r -> (tau_loc,ci,dh).
  int tloc[7];
  int cpart[7];
#pragma unroll
  for (int i = 0; i < 7; ++i) {
    int r = (tid >> 4) + 32 * i;
    if (r > 199) r = 199;                   // pad rows duplicate row 199
    int tl  = r / 10;
    int rem = r - tl * 10;
    int ci  = rem / 5;
    int dh  = rem - ci * 5;
    int hh = h + dh - 2;
    int hc = hh < 0 ? 0 : (hh > H - 1 ? H - 1 : hh);
    tloc[i]  = tl;
    cpart[i] = ((b * 2 + ci) * T) * HW + hc * 64 + (tid & 15) * 4;
  }

  const int tstore = chunk ? 175 : 0;
  const int ts     = chunk ? 145 : 0;       // 30-step warm-up (bitwise converged)
  const int te     = chunk ? 350 : 175;
  const int nsup   = (te - ts + 19) / 20;   // 9 or 11 supersteps (20 steps each)

  // Prologue: stage buffer 0 (taus ts+3 .. ts+22).
  {
    int bs = ts + 3;
#pragma unroll
    for (int i = 0; i < 7; ++i) {
      int tau = bs + tloc[i];
      if (tau > T - 1) tau = T - 1;
      gload_lds16(xT + (long)cpart[i] + (long)tau * HW,
                  &buf[0][(i * 32 + co * 4) * 64]);
    }
  }

  // Init sliding window (taus ts-2..ts+2) from global; slot = tau % 5.
  float win[2][5][5];
#pragma unroll
  for (int ci = 0; ci < 2; ++ci)
#pragma unroll
    for (int dh = 0; dh < 5; ++dh) {
      const float* bp = basep[ci][dh];
      win[ci][dh][3] = (ts >= 2) ? bp[(long)(ts - 2) * HW] : 0.0f;
      win[ci][dh][4] = (ts >= 1) ? bp[(long)(ts - 1) * HW] : 0.0f;
      win[ci][dh][0] = bp[(long)(ts + 0) * HW];
      win[ci][dh][1] = bp[(long)(ts + 1) * HW];
      win[ci][dh][2] = bp[(long)(ts + 2) * HW];
    }

  asm volatile("s_waitcnt vmcnt(0)" ::: "memory");
  __builtin_amdgcn_s_barrier();
  asm volatile("" ::: "memory");

  signed char* dsto = d8 + ((long)(b * T) * C1 + co) * HW + h * 64 + w;

  float y = 0.0f, sprev = 0.0f;
  for (int k = 0; k < nsup; ++k) {
    asm volatile("" ::: "memory");
    __builtin_amdgcn_s_barrier();           // prior readers of buf[(k+1)&1] done
    asm volatile("" ::: "memory");
    if (k + 1 < nsup) {
      int bs = ts + 3 + 20 * (k + 1);
      float* nb = &buf[(k + 1) & 1][0];
#pragma unroll
      for (int i = 0; i < 7; ++i) {
        int tau = bs + tloc[i];
        if (tau > T - 1) tau = T - 1;
        gload_lds16(xT + (long)cpart[i] + (long)tau * HW,
                    nb + (i * 32 + co * 4) * 64);
      }
      asm volatile("s_waitcnt vmcnt(7)" ::: "memory");
    } else {
      asm volatile("s_waitcnt vmcnt(0)" ::: "memory");
    }
    __builtin_amdgcn_s_barrier();           // everyone's buf[k&1] rows arrived
    asm volatile("" ::: "memory");

    float* lb = &buf[k & 1][0];
    {
      // zero rows whose tau >= T (only last superstep of chunk 1)
      int bufstart = ts + 3 + 20 * k;
      int rz0 = (T - bufstart) * 10;
      if (rz0 < 200) {
        if (rz0 < 0) rz0 = 0;
        for (int r = rz0 + co; r < 200; r += 8) lb[r * 64 + w] = 0.0f;
        asm volatile("" ::: "memory");
        __builtin_amdgcn_s_barrier();
        asm volatile("" ::: "memory");
      }
    }

    const int t0s = ts + 20 * k;
    for (int jj = 0; jj < 4; ++jj) {
#pragma unroll
      for (int u = 0; u < 5; ++u) {
        const int j5 = jj * 5;
        int t = t0s + j5 + u;
        float ac0 = 0.f, ac1 = 0.f, ac2 = 0.f, ac3 = 0.f;
#pragma unroll
        for (int ci = 0; ci < 2; ++ci)
#pragma unroll
          for (int dt = 0; dt < 5; ++dt) {
            const int slot = (u + dt + 3) % 5;
#pragma unroll
            for (int dh = 0; dh < 5; ++dh) {
              const int q = (ci * 25 + dt * 5 + dh) & 3;
              float p = win[ci][dh][slot] * wt[ci][dt][dh];
              if (q == 0) ac0 += p;
              else if (q == 1) ac1 += p;
              else if (q == 2) ac2 += p;
              else ac3 += p;
            }
          }
        float a = ((ac0 + ac1) + (ac2 + ac3)) + bias;
        a = fmaxf(a, 0.0f);
        y = fmaf(DEC, y, a);
        float s = (y >= 1.0f) ? 1.0f : 0.0f;
        if (t >= tstore && t < te) {
          float dlt = (t == 0) ? 0.0f : (s - sprev);
          dsto[(long)t * (C1 * HW)] = (signed char)dlt;
        }
        sprev = s;
        y = (s != 0.0f) ? 0.0f : y;
        // slide: tau = t+3 lives at LDS row (j*10 + ci*5 + dh)
        const int slot2 = (u + 3) % 5;
#pragma unroll
        for (int ci = 0; ci < 2; ++ci)
#pragma unroll
          for (int dh = 0; dh < 5; ++dh)
            win[ci][dh][slot2] = lb[((j5 + u) * 10 + ci * 5 + dh) * 64 + w];
      }
    }
  }
}

// ---------------------------------------------------------------------------
// Kernel B: deconv(2x2,s2) + bias + relu + conv2(1x1) + LIF2 -> out
// d8 [b][t][ci][hw]: ONE-TIME LDS gather of the block's 22t x 8ci x 64B tile
// (<=11 gload_lds16 issues, per-lane global gather -> linear LDS), then per
// pair-step 8 ds_read_u8 (lanes w0..3 share a dword -> broadcast, conflict-
// free). Compute + SB transposed flush identical to proven r10 stage2.
// 25 chunks of 28 t' -> 6400 blocks = 25 waves/CU.
// ---------------------------------------------------------------------------
__global__ void __launch_bounds__(64) stage2_kernel(
    const signed char* __restrict__ d8, const float* __restrict__ dw,
    const float* __restrict__ db, const float* __restrict__ cw,
    const float* __restrict__ cb, float* __restrict__ out) {
  __shared__ __align__(16) unsigned char lb8[176 * 64];   // 11 KiB tile
  __shared__ float SB[2][64][17];
  int bid   = blockIdx.x;
  int chunk = bid % 25;
  int rest  = bid / 25;
  int hp = rest & 127;
  int b  = rest >> 7;
  int wp = threadIdx.x;

  int h  = hp >> 1;
  int kh = 1 - (hp & 1);

  int t0 = chunk * 28;
  int t1 = t0 + 28;                         // 25*28 = 700 exactly
  int tw = (t0 - 16 > 0) ? t0 - 16 : 0;     // 16-step LIF2 warm-up (even)
  int twt = tw >> 1;
  int rows = ((t1 >> 1) - twt) * 8;         // 112 (chunk 0) or 176

  // One-time tile gather: row r = (t-twt)*8 + ci, 64B each (4 lanes x 16B).
  const signed char* dblk = d8 + ((long)(b * T) * C1) * HW + h * 64;
  int nissue = (rows + 15) >> 4;            // 7 or 11
  for (int i = 0; i < nissue; ++i) {
    int r = i * 16 + (wp >> 2);
    if (r > rows - 1) r = rows - 1;
    int t  = twt + (r >> 3);
    int ci = r & 7;
    gload_lds16(
        (const float*)(dblk + ((long)t * C1 + ci) * HW + (wp & 3) * 16),
        (float*)(&lb8[i * 1024]));
  }

  // deconv weights for this kh, both kt parities: dwk{kt}[c][ci]
  float dwk0[2][8], dwk1[2][8];
#pragma unroll
  for (int c = 0; c < 2; ++c)
#pragma unroll
    for (int ci = 0; ci < 8; ++ci) {
      dwk0[c][ci] = dw[((c * 8 + ci) * 2 + 0) * 2 + kh];
      dwk1[c][ci] = dw[((c * 8 + ci) * 2 + 1) * 2 + kh];
    }
  float db0 = db[0], db1 = db[1];
  float cw00 = cw[0], cw01 = cw[1], cw10 = cw[2], cw11 = cw[3];
  float cb0 = cb[0], cb1 = cb[1];

  asm volatile("s_waitcnt vmcnt(0)" ::: "memory");
  __syncthreads();                          // tile staged

  const unsigned char* lrow = &lb8[0] + wp;
  float* outb = out + ((long)b * 2 * HO) * (long)(WO * TO);

  float y0 = 0.0f, y1 = 0.0f;
  for (int tp = tw; tp < t1; tp += 2) {
    int tl = (tp >> 1) - twt;
    float dv[8];
#pragma unroll
    for (int ci = 0; ci < 8; ++ci)
      dv[ci] = (float)(signed char)lrow[(tl * 8 + ci) * 64];

#pragma unroll
    for (int par = 0; par < 2; ++par) {     // par=0: tp (kt=1), par=1: tp+1 (kt=0)
      int tpp = tp + par;
      float v0 = db0, v1 = db1;
      if (par == 0) {
#pragma unroll
        for (int ci = 0; ci < 8; ++ci) {
          v0 = fmaf(dv[ci], dwk1[0][ci], v0);
          v1 = fmaf(dv[ci], dwk1[1][ci], v1);
        }
      } else {
#pragma unroll
        for (int ci = 0; ci < 8; ++ci) {
          v0 = fmaf(dv[ci], dwk0[0][ci], v0);
          v1 = fmaf(dv[ci], dwk0[1][ci], v1);
        }
      }
      v0 = fmaxf(v0, 0.0f);
      v1 = fmaxf(v1, 0.0f);
      float u0 = fmaf(cw00, v0, fmaf(cw01, v1, cb0));
      float u1 = fmaf(cw10, v0, fmaf(cw11, v1, cb1));
      y0 = fmaf(DEC, y0, u0);
      y1 = fmaf(DEC, y1, u1);
      float s0 = (y0 >= 1.0f) ? 1.0f : 0.0f;
      float s1 = (y1 >= 1.0f) ? 1.0f : 0.0f;
      y0 = (s0 != 0.0f) ? 0.0f : y0;
      y1 = (s1 != 0.0f) ? 0.0f : y1;

      if (tpp >= t0) {
        int k = (tpp - t0) & 15;
        SB[0][wp][k] = s0;
        SB[1][wp][k] = s1;
        if (par == 1 && (k == 15 || tpp == t1 - 1)) {
          __syncthreads();
          int Kc  = k + 1;                  // 16 or 12 (both multiple of 4)
          int t0f = tpp - k;
#pragma unroll
          for (int o = 0; o < 2; ++o) {
            float* ob = outb + ((long)(o * HO + hp)) * (long)(WO * TO);
#pragma unroll
            for (int i = 0; i < 4; ++i) {
              int idx = (i << 6) + wp;
              int r   = idx >> 2;
              int c   = (idx & 3) << 2;
              if (c < Kc) {
                float4 vv;
                vv.x = SB[o][r][c + 0];
                vv.y = SB[o][r][c + 1];
                vv.z = SB[o][r][c + 2];
                vv.w = SB[o][r][c + 3];
                *reinterpret_cast<float4*>(ob + (long)r * TO + (t0f + c)) = vv;
              }
            }
          }
          __syncthreads();
        }
      }
    }
  }
}

// ---------------------------------------------------------------------------
extern "C" void kernel_launch(void* const* d_in, const int* in_sizes, int n_in,
                              void* d_out, int out_size, void* d_ws, size_t ws_size,
                              hipStream_t stream) {
  const float* x  = (const float*)d_in[0];
  const float* w1 = (const float*)d_in[1];
  const float* b1 = (const float*)d_in[2];
  const float* dw = (const float*)d_in[3];
  const float* db = (const float*)d_in[4];
  const float* cw = (const float*)d_in[5];
  const float* cb = (const float*)d_in[6];
  float* out = (float*)d_out;

  float* xT = (float*)d_ws;                                   // 22.94 MB
  signed char* d8 = (signed char*)d_ws + (size_t)B * CIN * T * HW * 4;  // +22.94 MB

  // 1) transpose x -> xT
  transpose_kernel<<<dim3(B * CIN * H * 6), dim3(256), 0, stream>>>(x, xT);
  // 2) conv1+relu+LIF1+delta -> d8 (round-4 verbatim: 2 chunks, S=20, 112KB)
  convlif_kernel<<<dim3(B * H * 2), dim3(512), 0, stream>>>(xT, w1, b1, d8);
  // 3) deconv+relu+conv2+LIF2 -> out (25 chunks, LDS-gathered tile)
  stage2_kernel<<<dim3(B * HO * 25), dim3(64), 0, stream>>>(d8, dw, db, cw, cb, out);
}

// Round 14
// 103.975 us; speedup vs baseline: 1.5778x; 1.2185x over previous
//
#include <hip/hip_runtime.h>

// Sizes (fixed for this problem)
constexpr int B  = 2,  CIN = 2,  H = 64, W = 64, T = 350;
constexpr int C1 = 8;                       // conv1 out channels
constexpr int TO = 700, HO = 128, WO = 64;
constexpr int HW = H * W;                   // 4096

#define DEC 0.05000000074505806f            // (float)(1.0 - 0.95)

// ---------------------------------------------------------------------------
// Kernel 0: transpose x [B,2,H,W,T] -> xT [B,2,T,H,W] so conv reads coalesce.
// ---------------------------------------------------------------------------
__global__ void __launch_bounds__(256) transpose_kernel(
    const float* __restrict__ x, float* __restrict__ xT) {
  __shared__ float tile[64][65];
  int bid   = blockIdx.x;
  int tTile = bid % 6;            // 6 tiles of 64 cover T=350
  int slice = bid / 6;            // (b*2+ci)*64 + h
  int h  = slice % H;
  int bc = slice / H;             // b*2+ci
  int t0 = tTile * 64;
  int tx = threadIdx.x & 63;
  int tz = threadIdx.x >> 6;      // 0..3

  const float* src = x + ((long)bc * H + h) * (long)(W * T);
#pragma unroll
  for (int i = 0; i < 16; ++i) {
    int w = tz * 16 + i;
    int t = t0 + tx;
    tile[w][tx] = (t < T) ? src[(long)w * T + t] : 0.0f;
  }
  __syncthreads();
  float* dst = xT + ((long)bc * T) * HW + h * 64;
#pragma unroll
  for (int i = 0; i < 16; ++i) {
    int tl = tz * 16 + i;
    int t  = t0 + tl;
    if (t < T) dst[(long)t * HW + tx] = tile[tx][tl];
  }
}

// ---------------------------------------------------------------------------
// async global->LDS, 16 bytes per lane (wave-uniform LDS base + lane*16)
// ---------------------------------------------------------------------------
__device__ __forceinline__ void gload_lds16(const float* g, float* l) {
  __builtin_amdgcn_global_load_lds(
      (const __attribute__((address_space(1))) unsigned int*)g,
      (__attribute__((address_space(3))) unsigned int*)l, 16, 0, 0);
}

// ---------------------------------------------------------------------------
// Kernel A: conv1(5x5 over T,H) + bias + relu + LIF1 + delta -> d8 int8
// d8 layout: [b][t][hw][ci] (stage2-uint2-friendly).
// 2-CO-PER-THREAD redesign (r13 analysis: 8 co-waves redundantly read the
// same window -> LDS pipe 464cyc/step AND VALU 460cyc/step both saturated).
// Block = 512 = (co-pair 0..3) x (h-sub 0..1) x (w 0..63): each thread's 10
// ds_read_b32/step now feed 100 FMAs (2 co share taps); block covers 2 h.
// Grid = B x H/2 x 4 chunks = 256 = EXACTLY 1 block/CU, single round,
// serial path 105 steps (was 205).
// LDS: 2 x 32KB input dbuf (S=10, 12 rows/tau for the 2-h union) + 10KB st.
// Weights = 100 VGPR/thread (NO launch_bounds cap -- standing rule).
// ---------------------------------------------------------------------------
__global__ void __launch_bounds__(512) convlif_kernel(
    const float* __restrict__ xT, const float* __restrict__ w1,
    const float* __restrict__ b1, signed char* __restrict__ d8) {
  __shared__ float buf[2][128 * 64];                    // 2 x 32 KiB
  __shared__ __align__(16) unsigned char st[10][1024];  // 10 KiB spikes
  const int tid = threadIdx.x;
  const int bid = blockIdx.x;
  const int chunk = bid & 3;
  const int rest  = bid >> 2;
  const int h2 = rest & 31;                 // h-pair index
  const int b  = rest >> 5;
  const int h0 = h2 * 2;
  const int w  = tid & 63;
  const int hs = (tid >> 6) & 1;            // wave h-sub
  const int cp = tid >> 7;                  // co-pair 0..3
  const int h  = h0 + hs;
  const int wid = tid >> 6;                 // wave id 0..7

  // chunk c of 4 (len 90,90,90,80): stored [90c, te); 15-step warm-up.
  const int tstore = chunk * 90;
  const int ts     = chunk ? tstore - 15 : 0;     // multiple of 5
  const int te     = tstore + 90 < T ? tstore + 90 : T;
  const int nsup   = (te - ts + 9) / 10;

  // Weights for co0=2cp, co1=2cp+1 (VGPR); zero taps with h+dh-2 OOB.
  float wt[2][2][5][5];
#pragma unroll
  for (int ci = 0; ci < 2; ++ci)
#pragma unroll
    for (int dh = 0; dh < 5; ++dh) {
      int hh = h + dh - 2;
      bool hv = (hh >= 0) && (hh < H);
#pragma unroll
      for (int dt = 0; dt < 5; ++dt) {
        wt[0][ci][dt][dh] = hv ? w1[(((cp*2+0) * 2 + ci) * 5 + dt) * 5 + dh] : 0.0f;
        wt[1][ci][dt][dh] = hv ? w1[(((cp*2+1) * 2 + ci) * 5 + dt) * 5 + dh] : 0.0f;
      }
    }
  float bias0 = b1[cp*2], bias1 = b1[cp*2+1];

  // Staging descriptors: 4 issues x 32 rows; row r = j*12 + ci*6 + dhh,
  // dhh in [0,6) covering h rows h0-2..h0+3 (union of both h-subs).
  int cdesc[4];
#pragma unroll
  for (int i = 0; i < 4; ++i) {
    int r = (tid >> 4) + 32 * i;
    if (r > 119) r = 119;                   // clamp SOURCE; dest rows <=127 ok
    int j   = r / 12;
    int rem = r - j * 12;
    int ci  = rem / 6;
    int dhh = rem - ci * 6;
    int hh = h0 + dhh - 2;
    int hc = hh < 0 ? 0 : (hh > H - 1 ? H - 1 : hh);
    cdesc[i] = (((b * 2 + ci) * T) * HW + hc * 64 + (tid & 15) * 4) | (j << 27);
  }

  // Prologue: stage buf[0] (taus ts+3 .. ts+12).
#pragma unroll
  for (int i = 0; i < 4; ++i) {
    int tau = ts + 3 + (cdesc[i] >> 27);
    if (tau > T - 1) tau = T - 1;
    gload_lds16(xT + (long)(cdesc[i] & 0x07ffffff) + (long)tau * HW,
                &buf[0][(i * 32 + wid * 4) * 64]);
  }

  // Window init (taus ts-2..ts+2) from global; slot = tau % 5 (ts%5==0).
  float win[2][5][5];
#pragma unroll
  for (int ci = 0; ci < 2; ++ci)
#pragma unroll
    for (int dh = 0; dh < 5; ++dh) {
      int hh = h + dh - 2;
      int hc = hh < 0 ? 0 : (hh > H - 1 ? H - 1 : hh);
      const float* bp = xT + ((long)((b * 2 + ci) * T)) * HW + hc * 64 + w;
      win[ci][dh][3] = (ts >= 2) ? bp[(long)(ts - 2) * HW] : 0.0f;
      win[ci][dh][4] = (ts >= 1) ? bp[(long)(ts - 1) * HW] : 0.0f;
      win[ci][dh][0] = bp[(long)(ts + 0) * HW];
      win[ci][dh][1] = bp[(long)(ts + 1) * HW];
      win[ci][dh][2] = bp[(long)(ts + 2) * HW];
    }

  asm volatile("s_waitcnt vmcnt(0)" ::: "memory");
  __builtin_amdgcn_s_barrier();
  asm volatile("" ::: "memory");

  signed char* const d8row = d8 + ((long)(b * T)) * (HW * C1) + h0 * 512;
  const int stw = ((hs * 64 + w) * 8 + cp * 2) >> 1;   // ushort index in row

  float y0 = 0.0f, y1 = 0.0f, sp0 = 0.0f, sp1 = 0.0f;
  for (int k = 0; k < nsup; ++k) {
    // barrier1: publish st writes of superstep k-1; next-buf readers done.
    asm volatile("s_waitcnt lgkmcnt(0)" ::: "memory");
    __builtin_amdgcn_s_barrier();
    asm volatile("" ::: "memory");

    // Flush superstep k-1 spikes (stores issued BEFORE staging loads so
    // vmcnt(4) drains them along with buffer-k loads).
    if (k > 0) {
      int tb = ts + 10 * (k - 1);
#pragma unroll
      for (int i = 0; i < 2; ++i) {
        int slot = tid + i * 512;
        if (slot < 640) {
          int u = slot >> 6;
          int c = (slot & 63) * 16;
          int t = tb + u;
          if (t >= tstore && t < te) {
            uint4 v = *reinterpret_cast<const uint4*>(&st[u][c]);
            *reinterpret_cast<uint4*>(d8row + (long)t * (HW * C1) + c) = v;
          }
        }
      }
    }

    if (k + 1 < nsup) {
      int bs = ts + 3 + 10 * (k + 1);
      float* nb = &buf[(k + 1) & 1][0];
#pragma unroll
      for (int i = 0; i < 4; ++i) {
        int tau = bs + (cdesc[i] >> 27);
        if (tau > T - 1) tau = T - 1;
        gload_lds16(xT + (long)(cdesc[i] & 0x07ffffff) + (long)tau * HW,
                    nb + (i * 32 + wid * 4) * 64);
      }
      asm volatile("s_waitcnt vmcnt(4)" ::: "memory");  // buf[k&1]+stores done
    } else {
      asm volatile("s_waitcnt vmcnt(0)" ::: "memory");
    }
    asm volatile("s_waitcnt lgkmcnt(0)" ::: "memory");
    __builtin_amdgcn_s_barrier();           // barrier2: buf[k&1] ready, st free
    asm volatile("" ::: "memory");

    float* lb = &buf[k & 1][0];
    {
      // zero rows whose tau >= T (final supersteps of last chunk only)
      int bufstart = ts + 3 + 10 * k;
      int rz0 = (T - bufstart) * 12;
      if (rz0 < 120) {
        if (rz0 < 0) rz0 = 0;
        for (int r = rz0 + wid; r < 120; r += 8) lb[r * 64 + w] = 0.0f;
        asm volatile("s_waitcnt lgkmcnt(0)" ::: "memory");
        __builtin_amdgcn_s_barrier();
        asm volatile("" ::: "memory");
      }
    }

    const int t0s = ts + 10 * k;
    for (int jj = 0; jj < 2; ++jj) {
#pragma unroll
      for (int u = 0; u < 5; ++u) {
        const int j5 = jj * 5;
        int t = t0s + j5 + u;
        float a0q0 = 0.f, a0q1 = 0.f, a0q2 = 0.f, a0q3 = 0.f;
        float a1q0 = 0.f, a1q1 = 0.f, a1q2 = 0.f, a1q3 = 0.f;
#pragma unroll
        for (int ci = 0; ci < 2; ++ci)
#pragma unroll
          for (int dt = 0; dt < 5; ++dt) {
            const int slot = (u + dt + 3) % 5;
#pragma unroll
            for (int dh = 0; dh < 5; ++dh) {
              const int q = (ci * 25 + dt * 5 + dh) & 3;
              float tap = win[ci][dh][slot];
              float p0 = tap * wt[0][ci][dt][dh];
              float p1 = tap * wt[1][ci][dt][dh];
              if (q == 0)      { a0q0 += p0; a1q0 += p1; }
              else if (q == 1) { a0q1 += p0; a1q1 += p1; }
              else if (q == 2) { a0q2 += p0; a1q2 += p1; }
              else             { a0q3 += p0; a1q3 += p1; }
            }
          }
        float a0 = fmaxf(((a0q0 + a0q1) + (a0q2 + a0q3)) + bias0, 0.0f);
        float a1 = fmaxf(((a1q0 + a1q1) + (a1q2 + a1q3)) + bias1, 0.0f);
        y0 = fmaf(DEC, y0, a0);
        y1 = fmaf(DEC, y1, a1);
        float s0 = (y0 >= 1.0f) ? 1.0f : 0.0f;
        float s1 = (y1 >= 1.0f) ? 1.0f : 0.0f;
        int d0 = (int)(s0 - sp0) & 0xff;
        int d1 = (int)(s1 - sp1) & 0xff;
        unsigned short val = (unsigned short)(d0 | (d1 << 8));
        if (t == 0) val = 0;
        reinterpret_cast<unsigned short*>(&st[j5 + u][0])[stw] = val;
        sp0 = s0; sp1 = s1;
        y0 = (s0 != 0.0f) ? 0.0f : y0;
        y1 = (s1 != 0.0f) ? 0.0f : y1;
        // slide: tau = t+3 at row ((j5+u)*12 + ci*6 + dh + hs)
        const int slot2 = (u + 3) % 5;
#pragma unroll
        for (int ci = 0; ci < 2; ++ci)
#pragma unroll
          for (int dh = 0; dh < 5; ++dh)
            win[ci][dh][slot2] =
                lb[((j5 + u) * 12 + ci * 6 + dh + hs) * 64 + w];
      }
    }
  }

  // Epilogue flush: last superstep's spikes.
  asm volatile("s_waitcnt lgkmcnt(0)" ::: "memory");
  __builtin_amdgcn_s_barrier();
  asm volatile("" ::: "memory");
  {
    int tb = ts + 10 * (nsup - 1);
#pragma unroll
    for (int i = 0; i < 2; ++i) {
      int slot = tid + i * 512;
      if (slot < 640) {
        int u = slot >> 6;
        int c = (slot & 63) * 16;
        int t = tb + u;
        if (t >= tstore && t < te) {
          uint4 v = *reinterpret_cast<const uint4*>(&st[u][c]);
          *reinterpret_cast<uint4*>(d8row + (long)t * (HW * C1) + c) = v;
        }
      }
    }
  }
}

// ---------------------------------------------------------------------------
// Kernel B: deconv(2x2,s2) + bias + relu + conv2(1x1) + LIF2 -> out
// d8 [b][t][hw][ci]: one 8B uint2 load per pair-step, prefetched 1 iter
// ahead. out [B,2,H',W',T']; LDS-staged transposed flush. 16 chunks of 44.
// (r9 verbatim -- part of the 120.1us best; r13's gather variant was ~46us,
// this one ~35us.)
// ---------------------------------------------------------------------------
__global__ void __launch_bounds__(64) stage2_kernel(
    const signed char* __restrict__ d8, const float* __restrict__ dw,
    const float* __restrict__ db, const float* __restrict__ cw,
    const float* __restrict__ cb, float* __restrict__ out) {
  __shared__ float SB[2][64][17];
  int bid   = blockIdx.x;
  int chunk = bid & 15;           // 16 chunks over T'=700
  int rest  = bid >> 4;
  int hp = rest & 127;            // h'
  int b  = rest >> 7;
  int wp = threadIdx.x;           // w'

  int h  = hp >> 1;
  int kh = 1 - (hp & 1);

  float dwk0[2][8], dwk1[2][8];
#pragma unroll
  for (int c = 0; c < 2; ++c)
#pragma unroll
    for (int ci = 0; ci < 8; ++ci) {
      dwk0[c][ci] = dw[((c * 8 + ci) * 2 + 0) * 2 + kh];
      dwk1[c][ci] = dw[((c * 8 + ci) * 2 + 1) * 2 + kh];
    }
  float db0 = db[0], db1 = db[1];
  float cw00 = cw[0], cw01 = cw[1], cw10 = cw[2], cw11 = cw[3];
  float cb0 = cb[0], cb1 = cb[1];

  int t0 = chunk * 44;
  int t1 = (t0 + 44 < TO) ? t0 + 44 : TO;   // last chunk: 40
  int tw = (t0 - 16 > 0) ? t0 - 16 : 0;     // 16-step LIF2 warm-up (even)

  const signed char* dbase = d8 + (((long)b * T) * HW + h * 64 + wp) * C1;
  const long tstride = (long)HW * C1;       // bytes per t
  float* outb = out + ((long)b * 2 * HO) * (long)(WO * TO);

  float y0 = 0.0f, y1 = 0.0f;
  uint2 dc = *reinterpret_cast<const uint2*>(dbase + (long)(tw >> 1) * tstride);
  for (int tp = tw; tp < t1; tp += 2) {
    int tn = (tp + 2 < t1) ? ((tp + 2) >> 1) : ((t1 - 1) >> 1);
    uint2 dn = *reinterpret_cast<const uint2*>(dbase + (long)tn * tstride);

    float dv[8];
#pragma unroll
    for (int ci = 0; ci < 4; ++ci) {
      dv[ci]     = (float)(signed char)((dc.x >> (8 * ci)) & 0xff);
      dv[ci + 4] = (float)(signed char)((dc.y >> (8 * ci)) & 0xff);
    }

#pragma unroll
    for (int par = 0; par < 2; ++par) {     // par=0: tp (kt=1), par=1: tp+1 (kt=0)
      int tpp = tp + par;
      float v0 = db0, v1 = db1;
      if (par == 0) {
#pragma unroll
        for (int ci = 0; ci < 8; ++ci) {
          v0 = fmaf(dv[ci], dwk1[0][ci], v0);
          v1 = fmaf(dv[ci], dwk1[1][ci], v1);
        }
      } else {
#pragma unroll
        for (int ci = 0; ci < 8; ++ci) {
          v0 = fmaf(dv[ci], dwk0[0][ci], v0);
          v1 = fmaf(dv[ci], dwk0[1][ci], v1);
        }
      }
      v0 = fmaxf(v0, 0.0f);
      v1 = fmaxf(v1, 0.0f);
      float u0 = fmaf(cw00, v0, fmaf(cw01, v1, cb0));
      float u1 = fmaf(cw10, v0, fmaf(cw11, v1, cb1));
      y0 = fmaf(DEC, y0, u0);
      y1 = fmaf(DEC, y1, u1);
      float s0 = (y0 >= 1.0f) ? 1.0f : 0.0f;
      float s1 = (y1 >= 1.0f) ? 1.0f : 0.0f;
      y0 = (s0 != 0.0f) ? 0.0f : y0;
      y1 = (s1 != 0.0f) ? 0.0f : y1;

      if (tpp >= t0) {
        int k = (tpp - t0) & 15;
        SB[0][wp][k] = s0;
        SB[1][wp][k] = s1;
        if (par == 1 && (k == 15 || tpp == t1 - 1)) {
          __syncthreads();
          int Kc  = k + 1;                  // 16 or a multiple of 4
          int t0f = tpp - k;
#pragma unroll
          for (int o = 0; o < 2; ++o) {
            float* ob = outb + ((long)(o * HO + hp)) * (long)(WO * TO);
#pragma unroll
            for (int i = 0; i < 4; ++i) {
              int idx = (i << 6) + wp;
              int r   = idx >> 2;
              int c   = (idx & 3) << 2;
              if (c < Kc) {
                float4 vv;
                vv.x = SB[o][r][c + 0];
                vv.y = SB[o][r][c + 1];
                vv.z = SB[o][r][c + 2];
                vv.w = SB[o][r][c + 3];
                *reinterpret_cast<float4*>(ob + (long)r * TO + (t0f + c)) = vv;
              }
            }
          }
          __syncthreads();
        }
      }
    }
    dc = dn;
  }
}

// ---------------------------------------------------------------------------
extern "C" void kernel_launch(void* const* d_in, const int* in_sizes, int n_in,
                              void* d_out, int out_size, void* d_ws, size_t ws_size,
                              hipStream_t stream) {
  const float* x  = (const float*)d_in[0];
  const float* w1 = (const float*)d_in[1];
  const float* b1 = (const float*)d_in[2];
  const float* dw = (const float*)d_in[3];
  const float* db = (const float*)d_in[4];
  const float* cw = (const float*)d_in[5];
  const float* cb = (const float*)d_in[6];
  float* out = (float*)d_out;

  float* xT = (float*)d_ws;                                   // 22.94 MB
  signed char* d8 = (signed char*)d_ws + (size_t)B * CIN * T * HW * 4;  // +22.94 MB

  // 1) transpose x -> xT
  transpose_kernel<<<dim3(B * CIN * H * 6), dim3(256), 0, stream>>>(x, xT);
  // 2) conv1+relu+LIF1+delta -> d8 (2-co/thread, 4 chunks, 256 blocks=1/CU)
  convlif_kernel<<<dim3(B * 32 * 4), dim3(512), 0, stream>>>(xT, w1, b1, d8);
  // 3) deconv+relu+conv2+LIF2 -> out (16 chunks, uint2 prefetch)
  stage2_kernel<<<dim3(B * HO * 16), dim3(64), 0, stream>>>(d8, dw, db, cw, cb, out);
}